// Round 3
// baseline (43.814 us; speedup 1.0000x reference)
//
#include <hip/hip_runtime.h>
#include <math.h>

#define BS 8
#define N_PTS 8192
#define N_SAMPLES 2048
#define THREADS 256
#define SPT 8                    // samples per thread: 256*8 = 2048 = full batch per block
#define PSPLIT 64
#define CHUNK (N_PTS / PSPLIT)   // 128 points per block
#define NTOT (BS * N_PTS)        // 65536 points per cloud

// ws layout: [0, 2*NTOT) float4  = packed {x,y,z,|p|^2} for preds then gts (2 MiB)
//            then 2*BS*N_SAMPLES uint = running-min bits (128 KiB)
#define WSMIN_OFF (2 * NTOT)     // in float4 units

// Prep: pack stride-3 points into float4 with |p|^2 in .w, and initialize the
// wsmin array to +huge (folds the former fillBuffer dispatch).
__global__ __launch_bounds__(THREADS)
void chamfer_prep_kernel(const float* __restrict__ gts,
                         const float* __restrict__ preds,
                         float4* __restrict__ ws)
{
    const int i = blockIdx.x * THREADS + threadIdx.x;   // 0 .. 2*NTOT-1
    const float* src = (i < NTOT) ? preds : gts;
    const int j = (i < NTOT) ? i : i - NTOT;
    const float x = src[j * 3 + 0];
    const float y = src[j * 3 + 1];
    const float z = src[j * 3 + 2];
    ws[i] = make_float4(x, y, z, fmaf(x, x, fmaf(y, y, z * z)));

    if (i < 2 * BS * N_SAMPLES) {
        unsigned int* wsmin = (unsigned int*)(ws + WSMIN_OFF);
        wsmin[i] = 0x7F7F7F7Fu;  // 3.39e38f as bits
    }
}

// Main: per (batch, point-chunk) block. Candidate metric per pair:
//   f = |p|^2 - 2 s.p   (monotone in d^2 for fixed s; d^2 = f + |s|^2)
// Point data is wave-uniform -> read via uniform address so it lands in SGPRs
// (s_load_dwordx4/x16, scalar pipe). Inner loop is pure VALU: 3 fma + min3
// shared over 2 candidates = 3.5 lane-ops per pair. No LDS, no syncthreads.
__global__ __launch_bounds__(THREADS, 1)
void chamfer_min_kernel(const float4* __restrict__ ws)
{
    const int bid = blockIdx.x;
    const int b   = bid / PSPLIT;
    const int pc  = bid % PSPLIT;
    const int t   = threadIdx.x;

    const float4* __restrict__ pp = ws + (size_t)b * N_PTS + (size_t)pc * CHUNK;          // preds chunk
    const float4* __restrict__ gg = ws + (size_t)(BS + b) * N_PTS + (size_t)pc * CHUNK;   // gts chunk

    // grid samples for this thread (coalesced: s = k*256 + t), ns = -2*s
    float nsx[SPT], nsy[SPT], nsz[SPT], mP[SPT], mG[SPT];
    {
        const float* grow = (const float*)0;  // set below
        const float* gridp;
        // grid_points is input 2; passed via ws? no — passed directly: see launch.
        (void)grow; (void)gridp;
    }
    // NOTE: grid pointer passed as second arg; see signature below.
    // (placeholder removed in actual definition)
    mP[0] = 0.f; // unreachable placeholder
}

// Real definition (with grid argument).
__global__ __launch_bounds__(THREADS, 1)
void chamfer_min_kernel2(const float4* __restrict__ ws,
                         const float* __restrict__ grid)
{
    const int bid = blockIdx.x;
    const int b   = bid / PSPLIT;
    const int pc  = bid % PSPLIT;
    const int t   = threadIdx.x;

    const float4* __restrict__ pp = ws + (size_t)b * N_PTS + (size_t)pc * CHUNK;
    const float4* __restrict__ gg = ws + (size_t)(BS + b) * N_PTS + (size_t)pc * CHUNK;

    float nsx[SPT], nsy[SPT], nsz[SPT], mP[SPT], mG[SPT];
    {
        const float* grow = grid + (size_t)b * N_SAMPLES * 3;
#pragma unroll
        for (int k = 0; k < SPT; ++k) {
            const int s = k * THREADS + t;
            nsx[k] = -2.0f * grow[s * 3 + 0];
            nsy[k] = -2.0f * grow[s * 3 + 1];
            nsz[k] = -2.0f * grow[s * 3 + 2];
            mP[k] = 3.0e38f;
            mG[k] = 3.0e38f;
        }
    }

    // 4 points per side per iter; point fetches are uniform -> scalar loads.
#pragma unroll 2
    for (int j = 0; j < CHUNK; j += 4) {
        const float4 p0 = pp[j], p1 = pp[j + 1], p2 = pp[j + 2], p3 = pp[j + 3];
        const float4 g0 = gg[j], g1 = gg[j + 1], g2 = gg[j + 2], g3 = gg[j + 3];
#pragma unroll
        for (int k = 0; k < SPT; ++k) {
            const float x = nsx[k], y = nsy[k], z = nsz[k];
            const float t0 = fmaf(p0.x, x, fmaf(p0.y, y, fmaf(p0.z, z, p0.w)));
            const float t1 = fmaf(p1.x, x, fmaf(p1.y, y, fmaf(p1.z, z, p1.w)));
            const float t2 = fmaf(p2.x, x, fmaf(p2.y, y, fmaf(p2.z, z, p2.w)));
            const float t3 = fmaf(p3.x, x, fmaf(p3.y, y, fmaf(p3.z, z, p3.w)));
            mP[k] = fminf(fminf(t0, t1), fminf(fminf(t2, t3), mP[k]));
            const float u0 = fmaf(g0.x, x, fmaf(g0.y, y, fmaf(g0.z, z, g0.w)));
            const float u1 = fmaf(g1.x, x, fmaf(g1.y, y, fmaf(g1.z, z, g1.w)));
            const float u2 = fmaf(g2.x, x, fmaf(g2.y, y, fmaf(g2.z, z, g2.w)));
            const float u3 = fmaf(g3.x, x, fmaf(g3.y, y, fmaf(g3.z, z, g3.w)));
            mG[k] = fminf(fminf(u0, u1), fminf(fminf(u2, u3), mG[k]));
        }
    }

    unsigned int* wsmin = (unsigned int*)(ws + WSMIN_OFF);
    unsigned int* wp = wsmin + (size_t)b * N_SAMPLES;
    unsigned int* wg = wsmin + (size_t)(BS + b) * N_SAMPLES;
#pragma unroll
    for (int k = 0; k < SPT; ++k) {
        const int s = k * THREADS + t;
        const float s2 = 0.25f * fmaf(nsx[k], nsx[k], fmaf(nsy[k], nsy[k], nsz[k] * nsz[k]));
        atomicMin(&wp[s], __float_as_uint(fmaxf(mP[k] + s2, 0.0f)));
        atomicMin(&wg[s], __float_as_uint(fmaxf(mG[k] + s2, 0.0f)));
    }
}

// Finish: per batch, |sqrt(minP2) - sqrt(minG2)| mean over samples.
__global__ __launch_bounds__(THREADS)
void chamfer_finish_kernel(const float4* __restrict__ ws,
                           float* __restrict__ out)
{
    const unsigned int* wsmin = (const unsigned int*)(ws + WSMIN_OFF);
    const int b = blockIdx.x;
    const int t = threadIdx.x;
    const unsigned int* wp = wsmin + (size_t)b * N_SAMPLES;
    const unsigned int* wg = wsmin + (size_t)(BS + b) * N_SAMPLES;

    float sum = 0.0f;
#pragma unroll
    for (int s = t; s < N_SAMPLES; s += THREADS) {
        const float dp = sqrtf(__uint_as_float(wp[s]));
        const float dg = sqrtf(__uint_as_float(wg[s]));
        sum += fabsf(dp - dg);
    }

#pragma unroll
    for (int off = 32; off > 0; off >>= 1)
        sum += __shfl_down(sum, off, 64);

    __shared__ float wsum[THREADS / 64];
    const int wid = t >> 6;
    if ((t & 63) == 0) wsum[wid] = sum;
    __syncthreads();
    if (t == 0) {
        float tot = 0.0f;
#pragma unroll
        for (int w = 0; w < THREADS / 64; ++w) tot += wsum[w];
        out[b] = tot / (float)N_SAMPLES;
    }
}

extern "C" void kernel_launch(void* const* d_in, const int* in_sizes, int n_in,
                              void* d_out, int out_size, void* d_ws, size_t ws_size,
                              hipStream_t stream)
{
    const float* gts   = (const float*)d_in[0];
    const float* preds = (const float*)d_in[1];
    const float* grid  = (const float*)d_in[2];
    float* out = (float*)d_out;
    float4* ws = (float4*)d_ws;

    chamfer_prep_kernel<<<dim3(2 * NTOT / THREADS), dim3(THREADS), 0, stream>>>(gts, preds, ws);
    chamfer_min_kernel2<<<dim3(BS * PSPLIT), dim3(THREADS), 0, stream>>>(ws, grid);
    chamfer_finish_kernel<<<dim3(BS), dim3(THREADS), 0, stream>>>(ws, out);
}